// Round 13
// baseline (1248.087 us; speedup 1.0000x reference)
//
#include <hip/hip_runtime.h>
#include <hip/hip_fp16.h>
#include <hip/hip_cooperative_groups.h>

namespace cg = cooperative_groups;

#define NEG_SLOPE 0.2f
#define NRANGE 8          // dst-range partitions (b%8, round-10 structure)
#define SCAN_TILE 2048
#define NBLK 1024         // 4 blocks/CU x 256 CUs — cooperative co-residency

__device__ __forceinline__ float elu_f(float x) {
    return x > 0.f ? x : __expf(x) - 1.f;
}
__device__ __forceinline__ float lrelu_f(float x) {
    return fmaxf(x, NEG_SLOPE * x);
}

union H4 { float2 f2; __half2 h2[2]; };

// ===========================================================================
// Cooperative single-dispatch pipeline.
// Round-12 fixes vs round-11 (which failed to LAUNCH, zero output):
//  * max static LDS cut 17408 -> 9216 B (gemm1 reads W1 from global, L1-hot)
//    so 4 blocks/CU is valid under the runtime's 64KB occupancy model.
//  * host checks the cooperative-launch return code and falls back to the
//    proven multi-kernel path (round-10, 341us) on any error.
// ===========================================================================
__global__ __launch_bounds__(256, 4) void fused_kernel(
    const float* __restrict__ x, const int* __restrict__ ei,
    const float* __restrict__ W1, const float* __restrict__ a_s1,
    const float* __restrict__ a_d1, const float* __restrict__ b1,
    const float* __restrict__ W2, const float* __restrict__ a_s2,
    const float* __restrict__ a_d2, const float* __restrict__ b2,
    const float* __restrict__ fcW, const float* __restrict__ fcb,
    float* __restrict__ as1, float* __restrict__ ad1,
    float* __restrict__ as2, float* __restrict__ ad2,
    __half* __restrict__ h1, __half* __restrict__ h2,
    int* __restrict__ cnt, int* __restrict__ rowptr,
    int* __restrict__ blocksum, unsigned short* __restrict__ srclist,
    float* __restrict__ out, int N, int E, int nScan)
{
    cg::grid_group grid = cg::this_grid();
    __shared__ union {
        struct { int lds[SCAN_TILE]; int tsum[256]; } sc;    // 9216 B (max)
        struct { float W2l[64 * 32]; float sh[4][64]; } ag;  // 9216 B
        float Xl[4][64];                                     // 1 KB (gemm1)
        int red[256];                                        // scanA
        int part[256];                                       // scanB
    } u;

    const int tid  = threadIdx.x;
    const int bid  = blockIdx.x;
    const int nblk = gridDim.x;
    const int gtid = bid * 256 + tid;
    const int gsz  = nblk * 256;

    // ---- P0: zero histogram (replaces hipMemsetAsync dispatch) ----
    for (int i = gtid; i < N; i += gsz) cnt[i] = 0;
    grid.sync();

    // ---- P1: histogram of dst (plain loads warm L3 for scatter passes) ----
    for (int t = gtid; t < E; t += gsz) atomicAdd(&cnt[ei[E + t]], 1);
    grid.sync();

    // ---- P2: scan phase A — per-tile sums (blocks [0,nScan)) ----
    if (bid < nScan) {
        int base = bid * SCAN_TILE;
        int s = 0;
#pragma unroll
        for (int k = 0; k < 8; ++k) {
            int i = base + k * 256 + tid;
            if (i < N) s += cnt[i];
        }
        u.red[tid] = s;
        __syncthreads();
        for (int off = 128; off; off >>= 1) {
            if (tid < off) u.red[tid] += u.red[tid + off];
            __syncthreads();
        }
        if (tid == 0) blocksum[bid] = u.red[0];
    }
    grid.sync();

    // ---- P3: scan phase B — exclusive scan of tile sums (block 0) ----
    if (bid == 0) {
        u.part[tid] = (tid < nScan) ? blocksum[tid] : 0;
        __syncthreads();
        for (int off = 1; off < 256; off <<= 1) {
            int v = (tid >= off) ? u.part[tid - off] : 0;
            __syncthreads();
            u.part[tid] += v;
            __syncthreads();
        }
        if (tid < nScan) blocksum[tid] = (tid == 0) ? 0 : u.part[tid - 1];
        if (tid == 0) rowptr[N] = E;
    }
    grid.sync();

    // ---- P4: scan phase C — tile-local scan + offset; rowptr & cursor ----
    if (bid < nScan) {
        int base = bid * SCAN_TILE;
#pragma unroll
        for (int k = 0; k < 8; ++k) {
            int i = base + k * 256 + tid;
            u.sc.lds[k * 256 + tid] = (i < N) ? cnt[i] : 0;
        }
        __syncthreads();
        int my[8];
        int s = 0;
#pragma unroll
        for (int j = 0; j < 8; ++j) { my[j] = s; s += u.sc.lds[tid * 8 + j]; }
        u.sc.tsum[tid] = s;
        __syncthreads();
        for (int off = 1; off < 256; off <<= 1) {
            int v = (tid >= off) ? u.sc.tsum[tid - off] : 0;
            __syncthreads();
            u.sc.tsum[tid] += v;
            __syncthreads();
        }
        int texcl = (tid == 0) ? 0 : u.sc.tsum[tid - 1];
        int boff = blocksum[bid];
        __syncthreads();
#pragma unroll
        for (int j = 0; j < 8; ++j) u.sc.lds[tid * 8 + j] = boff + texcl + my[j];
        __syncthreads();
#pragma unroll
        for (int k = 0; k < 8; ++k) {
            int i = base + k * 256 + tid;
            if (i < N) {
                int v = u.sc.lds[k * 256 + tid];
                rowptr[i] = v;
                cnt[i] = v;      // scatter cursor
            }
        }
    }
    grid.sync();

    // ---- P5: scatter (round-10 b%8 structure; per-node cursors) ----
    {
        int range = bid & (NRANGE - 1);
        int chunk = bid >> 3;
        const int nChunks = nblk >> 3;
        int RS = (N + NRANGE - 1) / NRANGE;
        int lo = range * RS;
        unsigned span = (unsigned)(((lo + RS) > N ? N : (lo + RS)) - lo);
        int per = (E + nChunks - 1) / nChunks;
        int beg = chunk * per;
        int end = beg + per; if (end > E) end = E;
        for (int i = beg + tid; i < end; i += 256) {
            int dst = ei[E + i];
            if ((unsigned)(dst - lo) < span) {
                int src = ei[i];
                int pos = atomicAdd(&cnt[dst], 1);
                srclist[pos] = (unsigned short)src;
            }
        }
    }
    grid.sync();

    // ---- P6: gemm1 (h1 fp16 + alpha1); W1 read from global (16KB, L1-hot) ----
    {
        int r   = tid >> 6;
        int col = tid & 63;
        int nG1 = (N + 3) / 4;
        for (int gb = bid; gb < nG1; gb += nblk) {
            int row = gb * 4 + r;
            __syncthreads();
            if (row < N) u.Xl[r][col] = x[(size_t)row * 64 + col];
            __syncthreads();
            if (row < N) {
                float acc = 0.f;
#pragma unroll
                for (int k = 0; k < 64; ++k) acc += u.Xl[r][k] * W1[k * 64 + col];
                h1[(size_t)row * 64 + col] = __float2half(acc);
                int head = col >> 5;
                float ps = acc * a_s1[col];
                float pd = acc * a_d1[col];
#pragma unroll
                for (int off = 16; off; off >>= 1) {
                    ps += __shfl_xor(ps, off, 32);
                    pd += __shfl_xor(pd, off, 32);
                }
                if ((col & 31) == 0) {
                    as1[row * 2 + head] = ps;
                    ad1[row * 2 + head] = pd;
                }
            }
        }
    }
    grid.sync();

    // ---- P7: agg1 + gemm2 + alpha2 (round-9/10 4-edge packed) ----
    {
        for (int i = tid; i < 64 * 32; i += 256) u.ag.W2l[i] = W2[i];
        __syncthreads();
        int lane = tid & 63;
        int wid  = tid >> 6;
        int grp = lane >> 4;
        int cl  = lane & 15;
        int head = cl >> 3;
        const __half* h1q = h1 + 4 * cl;
        int col = lane & 31;
        int kbase = (lane >> 5) * 32;
        int nG = (N + 3) / 4;
        for (int gb = bid; gb < nG; gb += nblk) {
            int n = gb * 4 + wid;
            if (n < N) {
                float adn = ad1[n * 2 + head];
                float den = 0.f, a0 = 0.f, a1 = 0.f, a2 = 0.f, a3 = 0.f;
                int beg = rowptr[n];
                int deg = rowptr[n + 1] - beg;
                int total = deg + 1;
                for (int base = 0; base < total; base += 64) {
                    int rem = total - base;
                    int cntc = rem > 64 ? 64 : rem;
                    int li = base + lane;
                    int es = (li < deg) ? (int)srclist[beg + li] : n;
                    int j = 0;
                    for (; j + 8 <= cntc; j += 8) {
                        int sA = __shfl(es, j + grp, 64);
                        int sB = __shfl(es, j + 4 + grp, 64);
                        float aA = as1[sA * 2 + head];
                        float aB = as1[sB * 2 + head];
                        H4 uA, uB;
                        uA.f2 = *(const float2*)(h1q + (size_t)sA * 64);
                        uB.f2 = *(const float2*)(h1q + (size_t)sB * 64);
                        float wA = __expf(lrelu_f(aA + adn));
                        float wB = __expf(lrelu_f(aB + adn));
                        float2 gA01 = __half22float2(uA.h2[0]);
                        float2 gA23 = __half22float2(uA.h2[1]);
                        float2 gB01 = __half22float2(uB.h2[0]);
                        float2 gB23 = __half22float2(uB.h2[1]);
                        den += wA + wB;
                        a0 += wA * gA01.x + wB * gB01.x;
                        a1 += wA * gA01.y + wB * gB01.y;
                        a2 += wA * gA23.x + wB * gB23.x;
                        a3 += wA * gA23.y + wB * gB23.y;
                    }
                    for (; j < cntc; j += 4) {
                        int e = j + grp;
                        int s = __shfl(es, e & 63, 64);
                        float a = as1[s * 2 + head];
                        H4 uu;
                        uu.f2 = *(const float2*)(h1q + (size_t)s * 64);
                        float w = (e < rem) ? __expf(lrelu_f(a + adn)) : 0.f;
                        float2 g01 = __half22float2(uu.h2[0]);
                        float2 g23 = __half22float2(uu.h2[1]);
                        den += w;
                        a0 += w * g01.x; a1 += w * g01.y;
                        a2 += w * g23.x; a3 += w * g23.y;
                    }
                }
                a0 += __shfl_xor(a0, 16, 64); a1 += __shfl_xor(a1, 16, 64);
                a2 += __shfl_xor(a2, 16, 64); a3 += __shfl_xor(a3, 16, 64);
                den += __shfl_xor(den, 16, 64);
                a0 += __shfl_xor(a0, 32, 64); a1 += __shfl_xor(a1, 32, 64);
                a2 += __shfl_xor(a2, 32, 64); a3 += __shfl_xor(a3, 32, 64);
                den += __shfl_xor(den, 32, 64);

                float4 bb = *(const float4*)(b1 + 4 * cl);
                float inv = 1.f / den;
                float v0 = elu_f(a0 * inv + bb.x);
                float v1 = elu_f(a1 * inv + bb.y);
                float v2 = elu_f(a2 * inv + bb.z);
                float v3 = elu_f(a3 * inv + bb.w);
                if (grp == 0) ((float4*)u.ag.sh[wid])[cl] = make_float4(v0, v1, v2, v3);
                // wave-internal LDS write->read: DS ops in-order per wave

                float p = 0.f;
#pragma unroll
                for (int jj = 0; jj < 32; ++jj)
                    p += u.ag.sh[wid][kbase + jj] * u.ag.W2l[(kbase + jj) * 32 + col];
                p += __shfl_xor(p, 32, 64);

                if (lane < 32) h2[(size_t)n * 32 + lane] = __float2half(p);

                float ps = p * a_s2[col];
                float pd = p * a_d2[col];
#pragma unroll
                for (int off = 16; off; off >>= 1) {
                    ps += __shfl_xor(ps, off, 32);
                    pd += __shfl_xor(pd, off, 32);
                }
                if (lane == 0) { as2[n] = ps; ad2[n] = pd; }
            }
        }
    }
    grid.sync();

    // ---- P8: agg2 + final FC (4-edge packed), 8 nodes/block-iter ----
    {
        int l32 = tid & 31;
        int grp = l32 >> 3;
        int cl  = l32 & 7;
        const __half* h2q = h2 + 4 * cl;
        int nG = (N + 7) / 8;
        for (int gb = bid; gb < nG; gb += nblk) {
            int n = gb * 8 + (tid >> 5);
            if (n < N) {
                float adn = ad2[n];
                float den = 0.f, a0 = 0.f, a1 = 0.f, a2 = 0.f, a3 = 0.f;
                int beg = rowptr[n];
                int deg = rowptr[n + 1] - beg;
                int total = deg + 1;
                for (int base = 0; base < total; base += 32) {
                    int rem = total - base;
                    int cntc = rem > 32 ? 32 : rem;
                    int li = base + l32;
                    int es = (li < deg) ? (int)srclist[beg + li] : n;
                    int j = 0;
                    for (; j + 8 <= cntc; j += 8) {
                        int sA = __shfl(es, j + grp, 32);
                        int sB = __shfl(es, j + 4 + grp, 32);
                        float aA = as2[sA];
                        float aB = as2[sB];
                        H4 uA, uB;
                        uA.f2 = *(const float2*)(h2q + (size_t)sA * 32);
                        uB.f2 = *(const float2*)(h2q + (size_t)sB * 32);
                        float wA = __expf(lrelu_f(aA + adn));
                        float wB = __expf(lrelu_f(aB + adn));
                        float2 gA01 = __half22float2(uA.h2[0]);
                        float2 gA23 = __half22float2(uA.h2[1]);
                        float2 gB01 = __half22float2(uB.h2[0]);
                        float2 gB23 = __half22float2(uB.h2[1]);
                        den += wA + wB;
                        a0 += wA * gA01.x + wB * gB01.x;
                        a1 += wA * gA01.y + wB * gB01.y;
                        a2 += wA * gA23.x + wB * gB23.x;
                        a3 += wA * gA23.y + wB * gB23.y;
                    }
                    for (; j < cntc; j += 4) {
                        int e = j + grp;
                        int s = __shfl(es, e & 31, 32);
                        float a = as2[s];
                        H4 uu;
                        uu.f2 = *(const float2*)(h2q + (size_t)s * 32);
                        float w = (e < rem) ? __expf(lrelu_f(a + adn)) : 0.f;
                        float2 g01 = __half22float2(uu.h2[0]);
                        float2 g23 = __half22float2(uu.h2[1]);
                        den += w;
                        a0 += w * g01.x; a1 += w * g01.y;
                        a2 += w * g23.x; a3 += w * g23.y;
                    }
                }
                a0 += __shfl_xor(a0, 8, 64);  a1 += __shfl_xor(a1, 8, 64);
                a2 += __shfl_xor(a2, 8, 64);  a3 += __shfl_xor(a3, 8, 64);
                den += __shfl_xor(den, 8, 64);
                a0 += __shfl_xor(a0, 16, 64); a1 += __shfl_xor(a1, 16, 64);
                a2 += __shfl_xor(a2, 16, 64); a3 += __shfl_xor(a3, 16, 64);
                den += __shfl_xor(den, 16, 64);

                float4 bb = *(const float4*)(b2 + 4 * cl);
                float inv = 1.f / den;
                float v0 = elu_f(a0 * inv + bb.x);
                float v1 = elu_f(a1 * inv + bb.y);
                float v2 = elu_f(a2 * inv + bb.z);
                float v3 = elu_f(a3 * inv + bb.w);
                if (grp == 0)
                    ((float4*)(out + (size_t)N + (size_t)n * 32))[cl] =
                        make_float4(v0, v1, v2, v3);

                float4 fw = *(const float4*)(fcW + 4 * cl);
                float p = v0 * fw.x + v1 * fw.y + v2 * fw.z + v3 * fw.w;
                p += __shfl_xor(p, 1, 64);
                p += __shfl_xor(p, 2, 64);
                p += __shfl_xor(p, 4, 64);
                if (l32 == 0) out[n] = p + fcb[0];
            }
        }
    }
}

// ===========================================================================
// Fallback multi-kernel pipeline (round-10, 341us, PASSED) — used only if
// the cooperative launch returns an error. Identical math.
// ===========================================================================
__global__ __launch_bounds__(256) void hist_kernel(
    const int* __restrict__ ei, int* __restrict__ cnt, int E)
{
    int t = blockIdx.x * 256 + threadIdx.x;
    if (t < E) atomicAdd(&cnt[ei[E + t]], 1);
}

__global__ __launch_bounds__(256) void scan_partial_kernel(
    const int* __restrict__ cnt, int* __restrict__ blocksum, int N)
{
    __shared__ int red[256];
    int base = blockIdx.x * SCAN_TILE;
    int s = 0;
#pragma unroll
    for (int k = 0; k < 8; ++k) {
        int i = base + k * 256 + threadIdx.x;
        if (i < N) s += cnt[i];
    }
    red[threadIdx.x] = s;
    __syncthreads();
    for (int off = 128; off; off >>= 1) {
        if (threadIdx.x < off) red[threadIdx.x] += red[threadIdx.x + off];
        __syncthreads();
    }
    if (threadIdx.x == 0) blocksum[blockIdx.x] = red[0];
}

__global__ __launch_bounds__(1024) void scan_blocksum_kernel(
    int* __restrict__ blocksum, int nb, int* __restrict__ rowptr, int N, int E)
{
    __shared__ int part[1024];
    int t = threadIdx.x;
    part[t] = (t < nb) ? blocksum[t] : 0;
    __syncthreads();
    for (int off = 1; off < 1024; off <<= 1) {
        int v = (t >= off) ? part[t - off] : 0;
        __syncthreads();
        part[t] += v;
        __syncthreads();
    }
    if (t < nb) blocksum[t] = (t == 0) ? 0 : part[t - 1];
    if (t == 0) rowptr[N] = E;
}

__global__ __launch_bounds__(256) void scan_final_kernel(
    int* __restrict__ cnt, const int* __restrict__ blocksum,
    int* __restrict__ rowptr, int N)
{
    __shared__ int lds[SCAN_TILE];
    __shared__ int tsum[256];
    int base = blockIdx.x * SCAN_TILE;
    int tid = threadIdx.x;
#pragma unroll
    for (int k = 0; k < 8; ++k) {
        int i = base + k * 256 + tid;
        lds[k * 256 + tid] = (i < N) ? cnt[i] : 0;
    }
    __syncthreads();
    int my[8];
    int s = 0;
#pragma unroll
    for (int j = 0; j < 8; ++j) { my[j] = s; s += lds[tid * 8 + j]; }
    tsum[tid] = s;
    __syncthreads();
    for (int off = 1; off < 256; off <<= 1) {
        int v = (tid >= off) ? tsum[tid - off] : 0;
        __syncthreads();
        tsum[tid] += v;
        __syncthreads();
    }
    int texcl = (tid == 0) ? 0 : tsum[tid - 1];
    int boff = blocksum[blockIdx.x];
    __syncthreads();
#pragma unroll
    for (int j = 0; j < 8; ++j) lds[tid * 8 + j] = boff + texcl + my[j];
    __syncthreads();
#pragma unroll
    for (int k = 0; k < 8; ++k) {
        int i = base + k * 256 + tid;
        if (i < N) {
            int v = lds[k * 256 + tid];
            rowptr[i] = v;
            cnt[i] = v;
        }
    }
}

__global__ __launch_bounds__(256) void scatter_kernel(
    const int* __restrict__ ei, int* __restrict__ cursor,
    unsigned short* __restrict__ srclist, int E, int N, int nChunks)
{
    int b = blockIdx.x;
    int range = b & (NRANGE - 1);
    int chunk = b >> 3;
    int RS = (N + NRANGE - 1) / NRANGE;
    int lo = range * RS;
    unsigned span = (unsigned)(((lo + RS) > N ? N : (lo + RS)) - lo);
    int per = (E + nChunks - 1) / nChunks;
    int beg = chunk * per;
    int end = beg + per; if (end > E) end = E;
    for (int i = beg + (int)threadIdx.x; i < end; i += 256) {
        int dst = ei[E + i];
        if ((unsigned)(dst - lo) < span) {
            int src = ei[i];
            int pos = atomicAdd(&cursor[dst], 1);
            srclist[pos] = (unsigned short)src;
        }
    }
}

__global__ __launch_bounds__(256) void gemm1_kernel(
    const float* __restrict__ x, const float* __restrict__ W,
    const float* __restrict__ a_src, const float* __restrict__ a_dst,
    __half* __restrict__ h1, float* __restrict__ as1, float* __restrict__ ad1,
    int N)
{
    __shared__ float Wl[64 * 64];
    __shared__ float Xl[4][64];
    int tid = threadIdx.x;
    for (int i = tid; i < 64 * 64; i += 256) Wl[i] = W[i];
    int r   = tid >> 6;
    int col = tid & 63;
    int row = blockIdx.x * 4 + r;
    if (row < N) Xl[r][col] = x[(size_t)row * 64 + col];
    __syncthreads();
    if (row >= N) return;

    float acc = 0.f;
#pragma unroll
    for (int k = 0; k < 64; ++k) acc += Xl[r][k] * Wl[k * 64 + col];
    h1[(size_t)row * 64 + col] = __float2half(acc);

    int head = col >> 5;
    float ps = acc * a_src[col];
    float pd = acc * a_dst[col];
#pragma unroll
    for (int off = 16; off; off >>= 1) {
        ps += __shfl_xor(ps, off, 32);
        pd += __shfl_xor(pd, off, 32);
    }
    if ((col & 31) == 0) {
        as1[row * 2 + head] = ps;
        ad1[row * 2 + head] = pd;
    }
}

__global__ __launch_bounds__(256) void agg1_gemm2_kernel(
    const int* __restrict__ rowptr, const unsigned short* __restrict__ srclist,
    const __half* __restrict__ h1, const float* __restrict__ as1,
    const float* __restrict__ ad1, const float* __restrict__ b1,
    const float* __restrict__ W2, const float* __restrict__ a_s2,
    const float* __restrict__ a_d2,
    __half* __restrict__ h2, float* __restrict__ as2, float* __restrict__ ad2,
    int N)
{
    __shared__ float W2l[64 * 32];
    __shared__ float sh[4][64];
    int tid = threadIdx.x;
    for (int i = tid; i < 64 * 32; i += 256) W2l[i] = W2[i];
    __syncthreads();

    int n = (blockIdx.x * 256 + tid) >> 6;
    int lane = tid & 63;
    int wid = tid >> 6;
    if (n >= N) return;

    int grp = lane >> 4;
    int cl  = lane & 15;
    int head = cl >> 3;
    float adn = ad1[n * 2 + head];
    const __half* h1q = h1 + 4 * cl;

    float den = 0.f, a0 = 0.f, a1 = 0.f, a2 = 0.f, a3 = 0.f;
    int beg = rowptr[n];
    int deg = rowptr[n + 1] - beg;
    int total = deg + 1;

    for (int base = 0; base < total; base += 64) {
        int rem = total - base;
        int cnt = rem > 64 ? 64 : rem;
        int li = base + lane;
        int es = (li < deg) ? (int)srclist[beg + li] : n;
        int j = 0;
        for (; j + 8 <= cnt; j += 8) {
            int sA = __shfl(es, j + grp, 64);
            int sB = __shfl(es, j + 4 + grp, 64);
            float aA = as1[sA * 2 + head];
            float aB = as1[sB * 2 + head];
            H4 uA, uB;
            uA.f2 = *(const float2*)(h1q + (size_t)sA * 64);
            uB.f2 = *(const float2*)(h1q + (size_t)sB * 64);
            float wA = __expf(lrelu_f(aA + adn));
            float wB = __expf(lrelu_f(aB + adn));
            float2 gA01 = __half22float2(uA.h2[0]);
            float2 gA23 = __half22float2(uA.h2[1]);
            float2 gB01 = __half22float2(uB.h2[0]);
            float2 gB23 = __half22float2(uB.h2[1]);
            den += wA + wB;
            a0 += wA * gA01.x + wB * gB01.x;
            a1 += wA * gA01.y + wB * gB01.y;
            a2 += wA * gA23.x + wB * gB23.x;
            a3 += wA * gA23.y + wB * gB23.y;
        }
        for (; j < cnt; j += 4) {
            int e = j + grp;
            int s = __shfl(es, e & 63, 64);
            float a = as1[s * 2 + head];
            H4 u;
            u.f2 = *(const float2*)(h1q + (size_t)s * 64);
            float w = (e < rem) ? __expf(lrelu_f(a + adn)) : 0.f;
            float2 g01 = __half22float2(u.h2[0]);
            float2 g23 = __half22float2(u.h2[1]);
            den += w;
            a0 += w * g01.x; a1 += w * g01.y;
            a2 += w * g23.x; a3 += w * g23.y;
        }
    }
    a0 += __shfl_xor(a0, 16, 64); a1 += __shfl_xor(a1, 16, 64);
    a2 += __shfl_xor(a2, 16, 64); a3 += __shfl_xor(a3, 16, 64);
    den += __shfl_xor(den, 16, 64);
    a0 += __shfl_xor(a0, 32, 64); a1 += __shfl_xor(a1, 32, 64);
    a2 += __shfl_xor(a2, 32, 64); a3 += __shfl_xor(a3, 32, 64);
    den += __shfl_xor(den, 32, 64);

    float4 bb = *(const float4*)(b1 + 4 * cl);
    float inv = 1.f / den;
    float v0 = elu_f(a0 * inv + bb.x);
    float v1 = elu_f(a1 * inv + bb.y);
    float v2 = elu_f(a2 * inv + bb.z);
    float v3 = elu_f(a3 * inv + bb.w);
    if (grp == 0) ((float4*)sh[wid])[cl] = make_float4(v0, v1, v2, v3);

    int col = lane & 31;
    int kbase = (lane >> 5) * 32;
    float p = 0.f;
#pragma unroll
    for (int jj = 0; jj < 32; ++jj)
        p += sh[wid][kbase + jj] * W2l[(kbase + jj) * 32 + col];
    p += __shfl_xor(p, 32, 64);

    if (lane < 32) h2[(size_t)n * 32 + lane] = __float2half(p);

    float ps = p * a_s2[col];
    float pd = p * a_d2[col];
#pragma unroll
    for (int off = 16; off; off >>= 1) {
        ps += __shfl_xor(ps, off, 32);
        pd += __shfl_xor(pd, off, 32);
    }
    if (lane == 0) { as2[n] = ps; ad2[n] = pd; }
}

__global__ __launch_bounds__(256) void agg2_kernel(
    const int* __restrict__ rowptr, const unsigned short* __restrict__ srclist,
    const __half* __restrict__ h2, const float* __restrict__ as2,
    const float* __restrict__ ad2, const float* __restrict__ b2,
    const float* __restrict__ fcW, const float* __restrict__ fcb,
    float* __restrict__ out, int N)
{
    int g = blockIdx.x * 256 + threadIdx.x;
    int n = g >> 5;
    if (n >= N) return;
    int l32 = g & 31;
    int grp = l32 >> 3;
    int cl  = l32 & 7;
    float adn = ad2[n];
    const __half* h2q = h2 + 4 * cl;

    float den = 0.f, a0 = 0.f, a1 = 0.f, a2 = 0.f, a3 = 0.f;
    int beg = rowptr[n];
    int deg = rowptr[n + 1] - beg;
    int total = deg + 1;

    for (int base = 0; base < total; base += 32) {
        int rem = total - base;
        int cnt = rem > 32 ? 32 : rem;
        int li = base + l32;
        int es = (li < deg) ? (int)srclist[beg + li] : n;
        int j = 0;
        for (; j + 8 <= cnt; j += 8) {
            int sA = __shfl(es, j + grp, 32);
            int sB = __shfl(es, j + 4 + grp, 32);
            float aA = as2[sA];
            float aB = as2[sB];
            H4 uA, uB;
            uA.f2 = *(const float2*)(h2q + (size_t)sA * 32);
            uB.f2 = *(const float2*)(h2q + (size_t)sB * 32);
            float wA = __expf(lrelu_f(aA + adn));
            float wB = __expf(lrelu_f(aB + adn));
            float2 gA01 = __half22float2(uA.h2[0]);
            float2 gA23 = __half22float2(uA.h2[1]);
            float2 gB01 = __half22float2(uB.h2[0]);
            float2 gB23 = __half22float2(uB.h2[1]);
            den += wA + wB;
            a0 += wA * gA01.x + wB * gB01.x;
            a1 += wA * gA01.y + wB * gB01.y;
            a2 += wA * gA23.x + wB * gB23.x;
            a3 += wA * gA23.y + wB * gB23.y;
        }
        for (; j < cnt; j += 4) {
            int e = j + grp;
            int s = __shfl(es, e & 31, 32);
            float a = as2[s];
            H4 u;
            u.f2 = *(const float2*)(h2q + (size_t)s * 32);
            float w = (e < rem) ? __expf(lrelu_f(a + adn)) : 0.f;
            float2 g01 = __half22float2(u.h2[0]);
            float2 g23 = __half22float2(u.h2[1]);
            den += w;
            a0 += w * g01.x; a1 += w * g01.y;
            a2 += w * g23.x; a3 += w * g23.y;
        }
    }
    a0 += __shfl_xor(a0, 8, 64);  a1 += __shfl_xor(a1, 8, 64);
    a2 += __shfl_xor(a2, 8, 64);  a3 += __shfl_xor(a3, 8, 64);
    den += __shfl_xor(den, 8, 64);
    a0 += __shfl_xor(a0, 16, 64); a1 += __shfl_xor(a1, 16, 64);
    a2 += __shfl_xor(a2, 16, 64); a3 += __shfl_xor(a3, 16, 64);
    den += __shfl_xor(den, 16, 64);

    float4 bb = *(const float4*)(b2 + 4 * cl);
    float inv = 1.f / den;
    float v0 = elu_f(a0 * inv + bb.x);
    float v1 = elu_f(a1 * inv + bb.y);
    float v2 = elu_f(a2 * inv + bb.z);
    float v3 = elu_f(a3 * inv + bb.w);
    if (grp == 0)
        ((float4*)(out + (size_t)N + (size_t)n * 32))[cl] =
            make_float4(v0, v1, v2, v3);

    float4 fw = *(const float4*)(fcW + 4 * cl);
    float p = v0 * fw.x + v1 * fw.y + v2 * fw.z + v3 * fw.w;
    p += __shfl_xor(p, 1, 64);
    p += __shfl_xor(p, 2, 64);
    p += __shfl_xor(p, 4, 64);
    if (l32 == 0) out[n] = p + fcb[0];
}

extern "C" void kernel_launch(void* const* d_in, const int* in_sizes, int n_in,
                              void* d_out, int out_size, void* d_ws, size_t ws_size,
                              hipStream_t stream) {
    const float* x    = (const float*)d_in[0];
    const int*   ei   = (const int*)d_in[1];
    const float* W1   = (const float*)d_in[2];
    const float* a_s1 = (const float*)d_in[3];
    const float* a_d1 = (const float*)d_in[4];
    const float* b1   = (const float*)d_in[5];
    const float* W2   = (const float*)d_in[6];
    const float* a_s2 = (const float*)d_in[7];
    const float* a_d2 = (const float*)d_in[8];
    const float* b2   = (const float*)d_in[9];
    const float* fcW  = (const float*)d_in[10];
    const float* fcb  = (const float*)d_in[11];

    int N = in_sizes[0] / 64;
    int E = in_sizes[1] / 2;
    int nScan = (N + SCAN_TILE - 1) / SCAN_TILE;

    // Workspace: fp32 arrays, then fp16 h2/h1, then ints, then ushort.
    float* fws  = (float*)d_ws;
    float* as1  = fws;                      // 2N
    float* ad1  = as1 + (size_t)2 * N;      // 2N
    float* as2  = ad1 + (size_t)2 * N;      // N
    float* ad2  = as2 + (size_t)N;          // N
    __half* h2  = (__half*)(ad2 + (size_t)N);       // 32N halves
    __half* h1  = h2 + (size_t)32 * N;              // 64N halves
    int*   cnt     = (int*)(h1 + (size_t)64 * N);   // N (histogram -> cursor)
    int*   rowptr  = cnt + N;                       // N+1
    int*   blocksum = rowptr + N + 1;               // nScan
    unsigned short* srclist = (unsigned short*)(blocksum + nScan);  // E

    float* out = (float*)d_out;

    void* args[] = {
        (void*)&x, (void*)&ei, (void*)&W1, (void*)&a_s1, (void*)&a_d1,
        (void*)&b1, (void*)&W2, (void*)&a_s2, (void*)&a_d2, (void*)&b2,
        (void*)&fcW, (void*)&fcb,
        (void*)&as1, (void*)&ad1, (void*)&as2, (void*)&ad2,
        (void*)&h1, (void*)&h2,
        (void*)&cnt, (void*)&rowptr, (void*)&blocksum, (void*)&srclist,
        (void*)&out, (void*)&N, (void*)&E, (void*)&nScan
    };
    hipError_t rc = hipLaunchCooperativeKernel((void*)fused_kernel, dim3(NBLK),
                                               dim3(256), args, 0, stream);
    if (rc == hipSuccess) return;

    // -------- fallback: proven round-10 multi-kernel pipeline --------
    hipMemsetAsync(cnt, 0, sizeof(int) * (size_t)N, stream);
    hist_kernel<<<(E + 255) / 256, 256, 0, stream>>>(ei, cnt, E);
    scan_partial_kernel<<<nScan, 256, 0, stream>>>(cnt, blocksum, N);
    scan_blocksum_kernel<<<1, 1024, 0, stream>>>(blocksum, nScan, rowptr, N, E);
    scan_final_kernel<<<nScan, 256, 0, stream>>>(cnt, blocksum, rowptr, N);
    const int nChunks = 256;
    scatter_kernel<<<nChunks * NRANGE, 256, 0, stream>>>(ei, cnt, srclist, E, N, nChunks);
    gemm1_kernel<<<(N + 3) / 4, 256, 0, stream>>>(x, W1, a_s1, a_d1, h1, as1, ad1, N);
    agg1_gemm2_kernel<<<((size_t)N * 64 + 255) / 256, 256, 0, stream>>>(
        rowptr, srclist, h1, as1, ad1, b1, W2, a_s2, a_d2, h2, as2, ad2, N);
    agg2_kernel<<<((size_t)N * 32 + 255) / 256, 256, 0, stream>>>(
        rowptr, srclist, h2, as2, ad2, b2, fcW, fcb, out, N);
}

// Round 14
// 324.024 us; speedup vs baseline: 3.8518x; 3.8518x over previous
//
#include <hip/hip_runtime.h>
#include <hip/hip_fp16.h>

#define NEG_SLOPE 0.2f
#define NRANGE 8          // dst-range partitions == XCD count (b%8 heuristic)
#define SCAN_TILE 2048    // elements per scan block

__device__ __forceinline__ float elu_f(float x) {
    return x > 0.f ? x : __expf(x) - 1.f;
}
__device__ __forceinline__ float lrelu_f(float x) {
    return fmaxf(x, NEG_SLOPE * x);
}

union H4 { float2 f2; __half2 h2[2]; };

// ---------------------------------------------------------------------------
// CSR build step 1: histogram of destination nodes. Plain loads: warms L3
// with ei so the scatter's 8 range-passes are L3-served (round-7 lesson).
// ---------------------------------------------------------------------------
__global__ __launch_bounds__(256) void hist_kernel(
    const int* __restrict__ ei, int* __restrict__ cnt, int E)
{
    int t = blockIdx.x * 256 + threadIdx.x;
    if (t < E) atomicAdd(&cnt[ei[E + t]], 1);
}

// ---------------------------------------------------------------------------
// Scan phases A+B merged: per-tile sums; the LAST block to finish (atomic
// counter) exclusive-scans the nScan (~25) tile sums in place and writes
// rowptr[N]=E. __threadfence (agent scope) on both sides of the atomic for
// cross-XCD visibility. Saves one dispatch + gap vs round-10.
// ---------------------------------------------------------------------------
__global__ __launch_bounds__(256) void scan_partialB_kernel(
    const int* __restrict__ cnt, int* __restrict__ blocksum,
    int* __restrict__ finish, int* __restrict__ rowptr,
    int N, int E, int nScan)
{
    __shared__ int red[256];
    int base = blockIdx.x * SCAN_TILE;
    int s = 0;
#pragma unroll
    for (int k = 0; k < 8; ++k) {
        int i = base + k * 256 + threadIdx.x;
        if (i < N) s += cnt[i];
    }
    red[threadIdx.x] = s;
    __syncthreads();
    for (int off = 128; off; off >>= 1) {
        if (threadIdx.x < off) red[threadIdx.x] += red[threadIdx.x + off];
        __syncthreads();
    }
    if (threadIdx.x == 0) {
        blocksum[blockIdx.x] = red[0];
        __threadfence();                       // release my blocksum
        int done = atomicAdd(finish, 1);
        if (done == nScan - 1) {               // I'm last
            __threadfence();                   // acquire others' blocksum
            int run = 0;
            for (int i = 0; i < nScan; ++i) {
                int t = blocksum[i];
                blocksum[i] = run;             // exclusive
                run += t;
            }
            rowptr[N] = E;
        }
    }
}

// ---------------------------------------------------------------------------
// Scan phase C: tile-local exclusive scan + tile offset; writes rowptr and
// scatter cursor (cursor aliases cnt). (Kernel boundary guarantees it sees
// the last block's blocksum values.)
// ---------------------------------------------------------------------------
__global__ __launch_bounds__(256) void scan_final_kernel(
    int* __restrict__ cnt, const int* __restrict__ blocksum,
    int* __restrict__ rowptr, int N)
{
    __shared__ int lds[SCAN_TILE];
    __shared__ int tsum[256];
    int base = blockIdx.x * SCAN_TILE;
    int tid = threadIdx.x;
#pragma unroll
    for (int k = 0; k < 8; ++k) {
        int i = base + k * 256 + tid;
        lds[k * 256 + tid] = (i < N) ? cnt[i] : 0;
    }
    __syncthreads();
    int my[8];
    int s = 0;
#pragma unroll
    for (int j = 0; j < 8; ++j) { my[j] = s; s += lds[tid * 8 + j]; }
    tsum[tid] = s;
    __syncthreads();
    for (int off = 1; off < 256; off <<= 1) {
        int v = (tid >= off) ? tsum[tid - off] : 0;
        __syncthreads();
        tsum[tid] += v;
        __syncthreads();
    }
    int texcl = (tid == 0) ? 0 : tsum[tid - 1];
    int boff = blocksum[blockIdx.x];
    __syncthreads();
#pragma unroll
    for (int j = 0; j < 8; ++j) lds[tid * 8 + j] = boff + texcl + my[j];
    __syncthreads();
#pragma unroll
    for (int k = 0; k < 8; ++k) {
        int i = base + k * 256 + tid;
        if (i < N) {
            int v = lds[k * 256 + tid];
            rowptr[i] = v;
            cnt[i] = v;      // scatter cursor
        }
    }
}

// ---------------------------------------------------------------------------
// Fused scatter + gemm1, INTERLEAVED roles (fix for round-6's additive
// result: FIFO dispatch had all 2048 scatter blocks first, so gemm1 never
// co-resided). Block b is scatter iff b%7==0 (within the first 7*SCB
// blocks): every resident cohort mixes both types, so the VALU-bound gemm1
// hides under the memory/atomic-bound scatter (VALUBusy 4%).
// LDS kept at 1 KB (gemm1 reads W1 from global, L1-hot 16 KB) so scatter
// occupancy is not LDS-capped (round-6 lesson: 17.4 KB -> 3 blocks/CU).
// Scatter: XCD-range-affine (sid&7; b=56k+7r => b%8 const per range),
// per-node cursors (round-4 lesson), plain loads (round-7 lesson).
// ---------------------------------------------------------------------------
__global__ __launch_bounds__(256) void scatter_gemm1_kernel(
    const int* __restrict__ ei, int* __restrict__ cursor,
    unsigned short* __restrict__ srclist, int E, int N, int nChunks,
    const float* __restrict__ x, const float* __restrict__ W1,
    const float* __restrict__ a_src, const float* __restrict__ a_dst,
    __half* __restrict__ h1, float* __restrict__ as1, float* __restrict__ ad1)
{
    __shared__ float Xl[4][64];
    const int SCB = nChunks * NRANGE;          // scatter block count
    int b = blockIdx.x;
    if (b < 7 * SCB && (b % 7) == 0) {
        // ---- scatter path ----
        int sid = b / 7;
        int range = sid & (NRANGE - 1);
        int chunk = sid >> 3;
        int RS = (N + NRANGE - 1) / NRANGE;
        int lo = range * RS;
        unsigned span = (unsigned)(((lo + RS) > N ? N : (lo + RS)) - lo);
        int per = (E + nChunks - 1) / nChunks;
        int beg = chunk * per;
        int end = beg + per; if (end > E) end = E;
        for (int i = beg + (int)threadIdx.x; i < end; i += 256) {
            int dst = ei[E + i];
            if ((unsigned)(dst - lo) < span) {
                int src = ei[i];
                int pos = atomicAdd(&cursor[dst], 1);
                srclist[pos] = (unsigned short)src;
            }
        }
        return;
    }
    // ---- gemm1 path ----
    int gid = (b < 7 * SCB) ? (b - b / 7 - 1) : (b - SCB);
    int tid = threadIdx.x;
    int r   = tid >> 6;
    int col = tid & 63;
    int row = gid * 4 + r;
    if (row < N) Xl[r][col] = x[(size_t)row * 64 + col];
    __syncthreads();
    if (row >= N) return;

    float acc = 0.f;
#pragma unroll
    for (int k = 0; k < 64; ++k) acc += Xl[r][k] * W1[k * 64 + col];
    h1[(size_t)row * 64 + col] = __float2half(acc);

    int head = col >> 5;
    float ps = acc * a_src[col];
    float pd = acc * a_dst[col];
#pragma unroll
    for (int off = 16; off; off >>= 1) {
        ps += __shfl_xor(ps, off, 32);
        pd += __shfl_xor(pd, off, 32);
    }
    if ((col & 31) == 0) {
        as1[row * 2 + head] = ps;
        ad1[row * 2 + head] = pd;
    }
}

// ---------------------------------------------------------------------------
// Fused layer-1 aggregation + GEMM2 + alpha2 (round-10, 4-edge packed,
// register-cached edge lists). Unchanged.
// ---------------------------------------------------------------------------
__global__ __launch_bounds__(256) void agg1_gemm2_kernel(
    const int* __restrict__ rowptr, const unsigned short* __restrict__ srclist,
    const __half* __restrict__ h1, const float* __restrict__ as1,
    const float* __restrict__ ad1, const float* __restrict__ b1,
    const float* __restrict__ W2, const float* __restrict__ a_s2,
    const float* __restrict__ a_d2,
    __half* __restrict__ h2, float* __restrict__ as2, float* __restrict__ ad2,
    int N)
{
    __shared__ float W2l[64 * 32];
    __shared__ float sh[4][64];
    int tid = threadIdx.x;
    for (int i = tid; i < 64 * 32; i += 256) W2l[i] = W2[i];
    __syncthreads();

    int n = (blockIdx.x * 256 + tid) >> 6;
    int lane = tid & 63;
    int wid = tid >> 6;
    if (n >= N) return;

    int grp = lane >> 4;
    int cl  = lane & 15;
    int head = cl >> 3;
    float adn = ad1[n * 2 + head];
    const __half* h1q = h1 + 4 * cl;

    float den = 0.f, a0 = 0.f, a1 = 0.f, a2 = 0.f, a3 = 0.f;
    int beg = rowptr[n];
    int deg = rowptr[n + 1] - beg;
    int total = deg + 1;

    for (int base = 0; base < total; base += 64) {
        int rem = total - base;
        int cnt = rem > 64 ? 64 : rem;
        int li = base + lane;
        int es = (li < deg) ? (int)srclist[beg + li] : n;
        int j = 0;
        for (; j + 8 <= cnt; j += 8) {
            int sA = __shfl(es, j + grp, 64);
            int sB = __shfl(es, j + 4 + grp, 64);
            float aA = as1[sA * 2 + head];
            float aB = as1[sB * 2 + head];
            H4 uA, uB;
            uA.f2 = *(const float2*)(h1q + (size_t)sA * 64);
            uB.f2 = *(const float2*)(h1q + (size_t)sB * 64);
            float wA = __expf(lrelu_f(aA + adn));
            float wB = __expf(lrelu_f(aB + adn));
            float2 gA01 = __half22float2(uA.h2[0]);
            float2 gA23 = __half22float2(uA.h2[1]);
            float2 gB01 = __half22float2(uB.h2[0]);
            float2 gB23 = __half22float2(uB.h2[1]);
            den += wA + wB;
            a0 += wA * gA01.x + wB * gB01.x;
            a1 += wA * gA01.y + wB * gB01.y;
            a2 += wA * gA23.x + wB * gB23.x;
            a3 += wA * gA23.y + wB * gB23.y;
        }
        for (; j < cnt; j += 4) {
            int e = j + grp;
            int s = __shfl(es, e & 63, 64);
            float a = as1[s * 2 + head];
            H4 u;
            u.f2 = *(const float2*)(h1q + (size_t)s * 64);
            float w = (e < rem) ? __expf(lrelu_f(a + adn)) : 0.f;
            float2 g01 = __half22float2(u.h2[0]);
            float2 g23 = __half22float2(u.h2[1]);
            den += w;
            a0 += w * g01.x; a1 += w * g01.y;
            a2 += w * g23.x; a3 += w * g23.y;
        }
    }
    a0 += __shfl_xor(a0, 16, 64); a1 += __shfl_xor(a1, 16, 64);
    a2 += __shfl_xor(a2, 16, 64); a3 += __shfl_xor(a3, 16, 64);
    den += __shfl_xor(den, 16, 64);
    a0 += __shfl_xor(a0, 32, 64); a1 += __shfl_xor(a1, 32, 64);
    a2 += __shfl_xor(a2, 32, 64); a3 += __shfl_xor(a3, 32, 64);
    den += __shfl_xor(den, 32, 64);

    float4 bb = *(const float4*)(b1 + 4 * cl);
    float inv = 1.f / den;
    float v0 = elu_f(a0 * inv + bb.x);
    float v1 = elu_f(a1 * inv + bb.y);
    float v2 = elu_f(a2 * inv + bb.z);
    float v3 = elu_f(a3 * inv + bb.w);
    if (grp == 0) ((float4*)sh[wid])[cl] = make_float4(v0, v1, v2, v3);
    // wave-internal LDS write->read: DS ops in-order per wave => coherent

    int col = lane & 31;
    int kbase = (lane >> 5) * 32;
    float p = 0.f;
#pragma unroll
    for (int jj = 0; jj < 32; ++jj)
        p += sh[wid][kbase + jj] * W2l[(kbase + jj) * 32 + col];
    p += __shfl_xor(p, 32, 64);

    if (lane < 32) h2[(size_t)n * 32 + lane] = __float2half(p);

    float ps = p * a_s2[col];
    float pd = p * a_d2[col];
#pragma unroll
    for (int off = 16; off; off >>= 1) {
        ps += __shfl_xor(ps, off, 32);
        pd += __shfl_xor(pd, off, 32);
    }
    if (lane == 0) { as2[n] = ps; ad2[n] = pd; }
}

// ---------------------------------------------------------------------------
// Layer-2 aggregation + final FC (round-10, 4-edge packed). Unchanged.
// out layout: [0,N) scores, [N, N+N*32) h
// ---------------------------------------------------------------------------
__global__ __launch_bounds__(256) void agg2_kernel(
    const int* __restrict__ rowptr, const unsigned short* __restrict__ srclist,
    const __half* __restrict__ h2, const float* __restrict__ as2,
    const float* __restrict__ ad2, const float* __restrict__ b2,
    const float* __restrict__ fcW, const float* __restrict__ fcb,
    float* __restrict__ out, int N)
{
    int g = blockIdx.x * 256 + threadIdx.x;
    int n = g >> 5;
    if (n >= N) return;
    int l32 = g & 31;
    int grp = l32 >> 3;
    int cl  = l32 & 7;
    float adn = ad2[n];
    const __half* h2q = h2 + 4 * cl;

    float den = 0.f, a0 = 0.f, a1 = 0.f, a2 = 0.f, a3 = 0.f;
    int beg = rowptr[n];
    int deg = rowptr[n + 1] - beg;
    int total = deg + 1;

    for (int base = 0; base < total; base += 32) {
        int rem = total - base;
        int cnt = rem > 32 ? 32 : rem;
        int li = base + l32;
        int es = (li < deg) ? (int)srclist[beg + li] : n;
        int j = 0;
        for (; j + 8 <= cnt; j += 8) {
            int sA = __shfl(es, j + grp, 32);
            int sB = __shfl(es, j + 4 + grp, 32);
            float aA = as2[sA];
            float aB = as2[sB];
            H4 uA, uB;
            uA.f2 = *(const float2*)(h2q + (size_t)sA * 32);
            uB.f2 = *(const float2*)(h2q + (size_t)sB * 32);
            float wA = __expf(lrelu_f(aA + adn));
            float wB = __expf(lrelu_f(aB + adn));
            float2 gA01 = __half22float2(uA.h2[0]);
            float2 gA23 = __half22float2(uA.h2[1]);
            float2 gB01 = __half22float2(uB.h2[0]);
            float2 gB23 = __half22float2(uB.h2[1]);
            den += wA + wB;
            a0 += wA * gA01.x + wB * gB01.x;
            a1 += wA * gA01.y + wB * gB01.y;
            a2 += wA * gA23.x + wB * gB23.x;
            a3 += wA * gA23.y + wB * gB23.y;
        }
        for (; j < cnt; j += 4) {
            int e = j + grp;
            int s = __shfl(es, e & 31, 32);
            float a = as2[s];
            H4 u;
            u.f2 = *(const float2*)(h2q + (size_t)s * 32);
            float w = (e < rem) ? __expf(lrelu_f(a + adn)) : 0.f;
            float2 g01 = __half22float2(u.h2[0]);
            float2 g23 = __half22float2(u.h2[1]);
            den += w;
            a0 += w * g01.x; a1 += w * g01.y;
            a2 += w * g23.x; a3 += w * g23.y;
        }
    }
    a0 += __shfl_xor(a0, 8, 64);  a1 += __shfl_xor(a1, 8, 64);
    a2 += __shfl_xor(a2, 8, 64);  a3 += __shfl_xor(a3, 8, 64);
    den += __shfl_xor(den, 8, 64);
    a0 += __shfl_xor(a0, 16, 64); a1 += __shfl_xor(a1, 16, 64);
    a2 += __shfl_xor(a2, 16, 64); a3 += __shfl_xor(a3, 16, 64);
    den += __shfl_xor(den, 16, 64);

    float4 bb = *(const float4*)(b2 + 4 * cl);
    float inv = 1.f / den;
    float v0 = elu_f(a0 * inv + bb.x);
    float v1 = elu_f(a1 * inv + bb.y);
    float v2 = elu_f(a2 * inv + bb.z);
    float v3 = elu_f(a3 * inv + bb.w);
    if (grp == 0)
        ((float4*)(out + (size_t)N + (size_t)n * 32))[cl] =
            make_float4(v0, v1, v2, v3);

    float4 fw = *(const float4*)(fcW + 4 * cl);
    float p = v0 * fw.x + v1 * fw.y + v2 * fw.z + v3 * fw.w;
    p += __shfl_xor(p, 1, 64);
    p += __shfl_xor(p, 2, 64);
    p += __shfl_xor(p, 4, 64);
    if (l32 == 0) out[n] = p + fcb[0];
}

extern "C" void kernel_launch(void* const* d_in, const int* in_sizes, int n_in,
                              void* d_out, int out_size, void* d_ws, size_t ws_size,
                              hipStream_t stream) {
    const float* x    = (const float*)d_in[0];
    const int*   ei   = (const int*)d_in[1];
    const float* W1   = (const float*)d_in[2];
    const float* a_s1 = (const float*)d_in[3];
    const float* a_d1 = (const float*)d_in[4];
    const float* b1   = (const float*)d_in[5];
    const float* W2   = (const float*)d_in[6];
    const float* a_s2 = (const float*)d_in[7];
    const float* a_d2 = (const float*)d_in[8];
    const float* b2   = (const float*)d_in[9];
    const float* fcW  = (const float*)d_in[10];
    const float* fcb  = (const float*)d_in[11];

    const int N = in_sizes[0] / 64;
    const int E = in_sizes[1] / 2;
    const int nScan = (N + SCAN_TILE - 1) / SCAN_TILE;

    // Workspace: fp32 arrays, then fp16 h2/h1, then ints, then ushort.
    float* fws  = (float*)d_ws;
    float* as1  = fws;                      // 2N
    float* ad1  = as1 + (size_t)2 * N;      // 2N
    float* as2  = ad1 + (size_t)2 * N;      // N
    float* ad2  = as2 + (size_t)N;          // N
    __half* h2  = (__half*)(ad2 + (size_t)N);       // 32N halves
    __half* h1  = h2 + (size_t)32 * N;              // 64N halves
    int*   cnt     = (int*)(h1 + (size_t)64 * N);   // N (histogram -> cursor)
    int*   finish  = cnt + N;                       // 1 (scan last-block ctr)
    int*   rowptr  = finish + 1;                    // N+1
    int*   blocksum = rowptr + N + 1;               // nScan
    unsigned short* srclist = (unsigned short*)(blocksum + nScan);  // E

    // one memset covers cnt[N] + finish[1]
    hipMemsetAsync(cnt, 0, sizeof(int) * ((size_t)N + 1), stream);

    hist_kernel<<<(E + 255) / 256, 256, 0, stream>>>(ei, cnt, E);

    scan_partialB_kernel<<<nScan, 256, 0, stream>>>(cnt, blocksum, finish,
                                                    rowptr, N, E, nScan);
    scan_final_kernel<<<nScan, 256, 0, stream>>>(cnt, blocksum, rowptr, N);

    // Interleaved scatter (SCB blocks, spread as b%7==0) + gemm1.
    const int nChunks = 256;
    const int SCB = nChunks * NRANGE;           // 2048
    const int nG1 = (N + 3) / 4;                // 12500
    int extra = nG1 - 6 * SCB; if (extra < 0) extra = 0;
    const int T = 7 * SCB + extra;              // 14548 for N=50000
    scatter_gemm1_kernel<<<T, 256, 0, stream>>>(
        ei, cnt, srclist, E, N, nChunks, x, W1, a_s1, a_d1, h1, as1, ad1);

    agg1_gemm2_kernel<<<((size_t)N * 64 + 255) / 256, 256, 0, stream>>>(
        rowptr, srclist, h1, as1, ad1, b1, W2, a_s2, a_d2, h2, as2, ad2, N);

    agg2_kernel<<<((size_t)N * 32 + 255) / 256, 256, 0, stream>>>(
        rowptr, srclist, h2, as2, ad2, b2, fcW, fcb, (float*)d_out, N);
}

// Round 15
// 315.593 us; speedup vs baseline: 3.9547x; 1.0267x over previous
//
#include <hip/hip_runtime.h>
#include <hip/hip_fp16.h>

#define NEG_SLOPE 0.2f
#define NRANGE 8          // dst-range partitions == XCD count (b%8 heuristic)
#define SCAN_TILE 2048    // elements per scan block

__device__ __forceinline__ float elu_f(float x) {
    return x > 0.f ? x : __expf(x) - 1.f;
}
__device__ __forceinline__ float lrelu_f(float x) {
    return fmaxf(x, NEG_SLOPE * x);
}

union H4 { float2 f2; __half2 h2[2]; };

// ---------------------------------------------------------------------------
// Fused hist + gemm1, INTERLEAVED roles (round-14 lesson: interleave by b%7
// so both types co-reside; FIFO dispatch killed the round-6 contiguous
// variant). hist is atomic/stream-bound (VALU ~0.3%), gemm1 VALU-bound —
// complementary pipes. hist also warms L3 with ei's dst column for the
// scatter kernel's 8 range passes (round-7 lesson: no nt hints).
// ---------------------------------------------------------------------------
__global__ __launch_bounds__(256) void hist_gemm1_kernel(
    const int* __restrict__ ei, int* __restrict__ cnt, int E, int N,
    int nHist,
    const float* __restrict__ x, const float* __restrict__ W1,
    const float* __restrict__ a_src, const float* __restrict__ a_dst,
    __half* __restrict__ h1, float* __restrict__ as1, float* __restrict__ ad1)
{
    __shared__ float Xl[4][64];
    int b = blockIdx.x;
    if (b < 7 * nHist && (b % 7) == 0) {
        // ---- hist path: virtual hist-block hid in [0,nHist), grid-stride ----
        int hid = b / 7;
        for (int t = hid * 256 + (int)threadIdx.x; t < E; t += nHist * 256)
            atomicAdd(&cnt[ei[E + t]], 1);
        return;
    }
    // ---- gemm1 path ----
    int gid = (b < 7 * nHist) ? (b - b / 7 - 1) : (b - nHist);
    int tid = threadIdx.x;
    int r   = tid >> 6;
    int col = tid & 63;
    int row = gid * 4 + r;
    if (row < N) Xl[r][col] = x[(size_t)row * 64 + col];
    __syncthreads();
    if (row >= N) return;

    float acc = 0.f;
#pragma unroll
    for (int k = 0; k < 64; ++k) acc += Xl[r][k] * W1[k * 64 + col];
    h1[(size_t)row * 64 + col] = __float2half(acc);

    int head = col >> 5;
    float ps = acc * a_src[col];
    float pd = acc * a_dst[col];
#pragma unroll
    for (int off = 16; off; off >>= 1) {
        ps += __shfl_xor(ps, off, 32);
        pd += __shfl_xor(pd, off, 32);
    }
    if ((col & 31) == 0) {
        as1[row * 2 + head] = ps;
        ad1[row * 2 + head] = pd;
    }
}

// ---------------------------------------------------------------------------
// Merged scan (phases A+B+C in ONE dispatch). Grid = nScan (=25) blocks,
// all trivially co-resident on 256 CUs, so an intra-kernel spin barrier is
// deadlock-free: each block writes its tile sum, the LAST finisher (atomic
// counter) exclusive-scans the 25 sums and releases flag; others spin with
// s_sleep. threadfence release/acquire around the flag. Then every block
// runs phase C on its own tile (writes rowptr + scatter cursor into cnt).
// Saves one dispatch + ~12us gap vs the round-14 two-kernel scan.
// ---------------------------------------------------------------------------
__global__ __launch_bounds__(256) void scan_merged_kernel(
    int* __restrict__ cnt, int* __restrict__ blocksum,
    int* __restrict__ finish, int* __restrict__ rowptr,
    int N, int E, int nScan)
{
    __shared__ int lds[SCAN_TILE];
    __shared__ int tsum[256];
    int base = blockIdx.x * SCAN_TILE;
    int tid = threadIdx.x;

    // ---- phase A: tile sum (also stage tile into LDS for phase C) ----
#pragma unroll
    for (int k = 0; k < 8; ++k) {
        int i = base + k * 256 + tid;
        lds[k * 256 + tid] = (i < N) ? cnt[i] : 0;
    }
    __syncthreads();
    int my[8];
    int s = 0;
#pragma unroll
    for (int j = 0; j < 8; ++j) { my[j] = s; s += lds[tid * 8 + j]; }
    tsum[tid] = s;
    __syncthreads();
    for (int off = 1; off < 256; off <<= 1) {
        int v = (tid >= off) ? tsum[tid - off] : 0;
        __syncthreads();
        tsum[tid] += v;
        __syncthreads();
    }

    // ---- phase B: last-finisher scans the nScan tile sums; others spin ----
    if (tid == 0) {
        blocksum[blockIdx.x] = tsum[255];
        __threadfence();                       // release my blocksum
        int done = atomicAdd(&finish[0], 1);
        if (done == nScan - 1) {
            __threadfence();                   // acquire all blocksums
            int run = 0;
            for (int i = 0; i < nScan; ++i) {
                int t = blocksum[i];
                blocksum[i] = run;             // exclusive
                run += t;
            }
            rowptr[N] = E;
            __threadfence();                   // release scanned blocksums
            atomicExch(&finish[1], 1);
        }
        while (atomicAdd(&finish[1], 0) == 0)  // spin: all 25 blocks resident
            __builtin_amdgcn_s_sleep(8);
        __threadfence();                       // acquire
    }
    __syncthreads();

    // ---- phase C: tile-local exclusive scan + offset ----
    int texcl = (tid == 0) ? 0 : tsum[tid - 1];
    int boff = blocksum[blockIdx.x];
    __syncthreads();
#pragma unroll
    for (int j = 0; j < 8; ++j) lds[tid * 8 + j] = boff + texcl + my[j];
    __syncthreads();
#pragma unroll
    for (int k = 0; k < 8; ++k) {
        int i = base + k * 256 + tid;
        if (i < N) {
            int v = lds[k * 256 + tid];
            rowptr[i] = v;
            cnt[i] = v;      // scatter cursor
        }
    }
}

// ---------------------------------------------------------------------------
// CSR scatter, standalone (round-10 exact, 73us): XCD-range-affine via b%8;
// per-node cursors (round-4 lesson: coarse cursors serialize); plain loads
// (round-7 lesson: L3-served re-passes). Round-11 lesson: do NOT pin to
// physical XCD id / work queues — 60MB writeback is intrinsic, 73us is this
// structure's plateau.
// ---------------------------------------------------------------------------
__global__ __launch_bounds__(256) void scatter_kernel(
    const int* __restrict__ ei, int* __restrict__ cursor,
    unsigned short* __restrict__ srclist, int E, int N, int nChunks)
{
    int b = blockIdx.x;
    int range = b & (NRANGE - 1);
    int chunk = b >> 3;
    int RS = (N + NRANGE - 1) / NRANGE;
    int lo = range * RS;
    unsigned span = (unsigned)(((lo + RS) > N ? N : (lo + RS)) - lo);
    int per = (E + nChunks - 1) / nChunks;
    int beg = chunk * per;
    int end = beg + per; if (end > E) end = E;
    for (int i = beg + (int)threadIdx.x; i < end; i += 256) {
        int dst = ei[E + i];
        if ((unsigned)(dst - lo) < span) {
            int src = ei[i];
            int pos = atomicAdd(&cursor[dst], 1);
            srclist[pos] = (unsigned short)src;
        }
    }
}

// ---------------------------------------------------------------------------
// Fused layer-1 aggregation + GEMM2 + alpha2 (round-10, 4-edge packed,
// register-cached edge lists). Unchanged.
// ---------------------------------------------------------------------------
__global__ __launch_bounds__(256) void agg1_gemm2_kernel(
    const int* __restrict__ rowptr, const unsigned short* __restrict__ srclist,
    const __half* __restrict__ h1, const float* __restrict__ as1,
    const float* __restrict__ ad1, const float* __restrict__ b1,
    const float* __restrict__ W2, const float* __restrict__ a_s2,
    const float* __restrict__ a_d2,
    __half* __restrict__ h2, float* __restrict__ as2, float* __restrict__ ad2,
    int N)
{
    __shared__ float W2l[64 * 32];
    __shared__ float sh[4][64];
    int tid = threadIdx.x;
    for (int i = tid; i < 64 * 32; i += 256) W2l[i] = W2[i];
    __syncthreads();

    int n = (blockIdx.x * 256 + tid) >> 6;
    int lane = tid & 63;
    int wid = tid >> 6;
    if (n >= N) return;

    int grp = lane >> 4;
    int cl  = lane & 15;
    int head = cl >> 3;
    float adn = ad1[n * 2 + head];
    const __half* h1q = h1 + 4 * cl;

    float den = 0.f, a0 = 0.f, a1 = 0.f, a2 = 0.f, a3 = 0.f;
    int beg = rowptr[n];
    int deg = rowptr[n + 1] - beg;
    int total = deg + 1;

    for (int base = 0; base < total; base += 64) {
        int rem = total - base;
        int cnt = rem > 64 ? 64 : rem;
        int li = base + lane;
        int es = (li < deg) ? (int)srclist[beg + li] : n;
        int j = 0;
        for (; j + 8 <= cnt; j += 8) {
            int sA = __shfl(es, j + grp, 64);
            int sB = __shfl(es, j + 4 + grp, 64);
            float aA = as1[sA * 2 + head];
            float aB = as1[sB * 2 + head];
            H4 uA, uB;
            uA.f2 = *(const float2*)(h1q + (size_t)sA * 64);
            uB.f2 = *(const float2*)(h1q + (size_t)sB * 64);
            float wA = __expf(lrelu_f(aA + adn));
            float wB = __expf(lrelu_f(aB + adn));
            float2 gA01 = __half22float2(uA.h2[0]);
            float2 gA23 = __half22float2(uA.h2[1]);
            float2 gB01 = __half22float2(uB.h2[0]);
            float2 gB23 = __half22float2(uB.h2[1]);
            den += wA + wB;
            a0 += wA * gA01.x + wB * gB01.x;
            a1 += wA * gA01.y + wB * gB01.y;
            a2 += wA * gA23.x + wB * gB23.x;
            a3 += wA * gA23.y + wB * gB23.y;
        }
        for (; j < cnt; j += 4) {
            int e = j + grp;
            int s = __shfl(es, e & 63, 64);
            float a = as1[s * 2 + head];
            H4 u;
            u.f2 = *(const float2*)(h1q + (size_t)s * 64);
            float w = (e < rem) ? __expf(lrelu_f(a + adn)) : 0.f;
            float2 g01 = __half22float2(u.h2[0]);
            float2 g23 = __half22float2(u.h2[1]);
            den += w;
            a0 += w * g01.x; a1 += w * g01.y;
            a2 += w * g23.x; a3 += w * g23.y;
        }
    }
    a0 += __shfl_xor(a0, 16, 64); a1 += __shfl_xor(a1, 16, 64);
    a2 += __shfl_xor(a2, 16, 64); a3 += __shfl_xor(a3, 16, 64);
    den += __shfl_xor(den, 16, 64);
    a0 += __shfl_xor(a0, 32, 64); a1 += __shfl_xor(a1, 32, 64);
    a2 += __shfl_xor(a2, 32, 64); a3 += __shfl_xor(a3, 32, 64);
    den += __shfl_xor(den, 32, 64);

    float4 bb = *(const float4*)(b1 + 4 * cl);
    float inv = 1.f / den;
    float v0 = elu_f(a0 * inv + bb.x);
    float v1 = elu_f(a1 * inv + bb.y);
    float v2 = elu_f(a2 * inv + bb.z);
    float v3 = elu_f(a3 * inv + bb.w);
    if (grp == 0) ((float4*)sh[wid])[cl] = make_float4(v0, v1, v2, v3);
    // wave-internal LDS write->read: DS ops in-order per wave => coherent

    int col = lane & 31;
    int kbase = (lane >> 5) * 32;
    float p = 0.f;
#pragma unroll
    for (int jj = 0; jj < 32; ++jj)
        p += sh[wid][kbase + jj] * W2l[(kbase + jj) * 32 + col];
    p += __shfl_xor(p, 32, 64);

    if (lane < 32) h2[(size_t)n * 32 + lane] = __float2half(p);

    float ps = p * a_s2[col];
    float pd = p * a_d2[col];
#pragma unroll
    for (int off = 16; off; off >>= 1) {
        ps += __shfl_xor(ps, off, 32);
        pd += __shfl_xor(pd, off, 32);
    }
    if (lane == 0) { as2[n] = ps; ad2[n] = pd; }
}

// ---------------------------------------------------------------------------
// Layer-2 aggregation + final FC (round-10, 4-edge packed). Unchanged.
// out layout: [0,N) scores, [N, N+N*32) h
// ---------------------------------------------------------------------------
__global__ __launch_bounds__(256) void agg2_kernel(
    const int* __restrict__ rowptr, const unsigned short* __restrict__ srclist,
    const __half* __restrict__ h2, const float* __restrict__ as2,
    const float* __restrict__ ad2, const float* __restrict__ b2,
    const float* __restrict__ fcW, const float* __restrict__ fcb,
    float* __restrict__ out, int N)
{
    int g = blockIdx.x * 256 + threadIdx.x;
    int n = g >> 5;
    if (n >= N) return;
    int l32 = g & 31;
    int grp = l32 >> 3;
    int cl  = l32 & 7;
    float adn = ad2[n];
    const __half* h2q = h2 + 4 * cl;

    float den = 0.f, a0 = 0.f, a1 = 0.f, a2 = 0.f, a3 = 0.f;
    int beg = rowptr[n];
    int deg = rowptr[n + 1] - beg;
    int total = deg + 1;

    for (int base = 0; base < total; base += 32) {
        int rem = total - base;
        int cnt = rem > 32 ? 32 : rem;
        int li = base + l32;
        int es = (li < deg) ? (int)srclist[beg + li] : n;
        int j = 0;
        for (; j + 8 <= cnt; j += 8) {
            int sA = __shfl(es, j + grp, 32);
            int sB = __shfl(es, j + 4 + grp, 32);
            float aA = as2[sA];
            float aB = as2[sB];
            H4 uA, uB;
            uA.f2 = *(const float2*)(h2q + (size_t)sA * 32);
            uB.f2 = *(const float2*)(h2q + (size_t)sB * 32);
            float wA = __expf(lrelu_f(aA + adn));
            float wB = __expf(lrelu_f(aB + adn));
            float2 gA01 = __half22float2(uA.h2[0]);
            float2 gA23 = __half22float2(uA.h2[1]);
            float2 gB01 = __half22float2(uB.h2[0]);
            float2 gB23 = __half22float2(uB.h2[1]);
            den += wA + wB;
            a0 += wA * gA01.x + wB * gB01.x;
            a1 += wA * gA01.y + wB * gB01.y;
            a2 += wA * gA23.x + wB * gB23.x;
            a3 += wA * gA23.y + wB * gB23.y;
        }
        for (; j < cnt; j += 4) {
            int e = j + grp;
            int s = __shfl(es, e & 31, 32);
            float a = as2[s];
            H4 u;
            u.f2 = *(const float2*)(h2q + (size_t)s * 32);
            float w = (e < rem) ? __expf(lrelu_f(a + adn)) : 0.f;
            float2 g01 = __half22float2(u.h2[0]);
            float2 g23 = __half22float2(u.h2[1]);
            den += w;
            a0 += w * g01.x; a1 += w * g01.y;
            a2 += w * g23.x; a3 += w * g23.y;
        }
    }
    a0 += __shfl_xor(a0, 8, 64);  a1 += __shfl_xor(a1, 8, 64);
    a2 += __shfl_xor(a2, 8, 64);  a3 += __shfl_xor(a3, 8, 64);
    den += __shfl_xor(den, 8, 64);
    a0 += __shfl_xor(a0, 16, 64); a1 += __shfl_xor(a1, 16, 64);
    a2 += __shfl_xor(a2, 16, 64); a3 += __shfl_xor(a3, 16, 64);
    den += __shfl_xor(den, 16, 64);

    float4 bb = *(const float4*)(b2 + 4 * cl);
    float inv = 1.f / den;
    float v0 = elu_f(a0 * inv + bb.x);
    float v1 = elu_f(a1 * inv + bb.y);
    float v2 = elu_f(a2 * inv + bb.z);
    float v3 = elu_f(a3 * inv + bb.w);
    if (grp == 0)
        ((float4*)(out + (size_t)N + (size_t)n * 32))[cl] =
            make_float4(v0, v1, v2, v3);

    float4 fw = *(const float4*)(fcW + 4 * cl);
    float p = v0 * fw.x + v1 * fw.y + v2 * fw.z + v3 * fw.w;
    p += __shfl_xor(p, 1, 64);
    p += __shfl_xor(p, 2, 64);
    p += __shfl_xor(p, 4, 64);
    if (l32 == 0) out[n] = p + fcb[0];
}

extern "C" void kernel_launch(void* const* d_in, const int* in_sizes, int n_in,
                              void* d_out, int out_size, void* d_ws, size_t ws_size,
                              hipStream_t stream) {
    const float* x    = (const float*)d_in[0];
    const int*   ei   = (const int*)d_in[1];
    const float* W1   = (const float*)d_in[2];
    const float* a_s1 = (const float*)d_in[3];
    const float* a_d1 = (const float*)d_in[4];
    const float* b1   = (const float*)d_in[5];
    const float* W2   = (const float*)d_in[6];
    const float* a_s2 = (const float*)d_in[7];
    const float* a_d2 = (const float*)d_in[8];
    const float* b2   = (const float*)d_in[9];
    const float* fcW  = (const float*)d_in[10];
    const float* fcb  = (const float*)d_in[11];

    const int N = in_sizes[0] / 64;
    const int E = in_sizes[1] / 2;
    const int nScan = (N + SCAN_TILE - 1) / SCAN_TILE;

    // Workspace: fp32 arrays, then fp16 h2/h1, then ints, then ushort.
    float* fws  = (float*)d_ws;
    float* as1  = fws;                      // 2N
    float* ad1  = as1 + (size_t)2 * N;      // 2N
    float* as2  = ad1 + (size_t)2 * N;      // N
    float* ad2  = as2 + (size_t)N;          // N
    __half* h2  = (__half*)(ad2 + (size_t)N);       // 32N halves
    __half* h1  = h2 + (size_t)32 * N;              // 64N halves
    int*   cnt     = (int*)(h1 + (size_t)64 * N);   // N (histogram -> cursor)
    int*   finish  = cnt + N;                       // 2 (scan arrival + flag)
    int*   rowptr  = finish + 2;                    // N+1
    int*   blocksum = rowptr + N + 1;               // nScan
    unsigned short* srclist = (unsigned short*)(blocksum + nScan);  // E

    // one memset covers cnt[N] + finish[2]
    hipMemsetAsync(cnt, 0, sizeof(int) * ((size_t)N + 2), stream);

    // Fused hist + gemm1 (interleaved roles, b%7==0 -> hist).
    const int nHist = 2048;
    const int nG1 = (N + 3) / 4;
    int extra = nG1 - 6 * nHist; if (extra < 0) extra = 0;
    hist_gemm1_kernel<<<7 * nHist + extra, 256, 0, stream>>>(
        ei, cnt, E, N, nHist, x, W1, a_s1, a_d1, h1, as1, ad1);

    // Single-dispatch merged scan (25 co-resident blocks + spin barrier).
    scan_merged_kernel<<<nScan, 256, 0, stream>>>(cnt, blocksum, finish,
                                                  rowptr, N, E, nScan);

    const int nChunks = 256;
    scatter_kernel<<<nChunks * NRANGE, 256, 0, stream>>>(ei, cnt, srclist, E, N, nChunks);

    agg1_gemm2_kernel<<<((size_t)N * 64 + 255) / 256, 256, 0, stream>>>(
        rowptr, srclist, h1, as1, ad1, b1, W2, a_s2, a_d2, h2, as2, ad2, N);

    agg2_kernel<<<((size_t)N * 32 + 255) / 256, 256, 0, stream>>>(
        rowptr, srclist, h2, as2, ad2, b2, fcW, fcb, (float*)d_out, N);
}